// Round 9
// baseline (591.155 us; speedup 1.0000x reference)
//
#include <hip/hip_runtime.h>
#include <cstddef>
#include <cstdint>

#define SEQ    2048
#define DMODEL 1024
#define NH     16
#define HD     64
#define NB     2

typedef __attribute__((ext_vector_type(8))) short short8;
typedef __attribute__((ext_vector_type(4))) float floatx4;

#define MFMA16(a, b, c) __builtin_amdgcn_mfma_f32_16x16x32_bf16((a), (b), (c), 0, 0, 0)

// async 16B global->LDS (wave-uniform base + lane*16 ordering honored by callers)
#define ASYNC16(gsrc, ldst) \
    __builtin_amdgcn_global_load_lds((const __attribute__((address_space(1))) void*)(gsrc), \
                                     (__attribute__((address_space(3))) void*)(ldst), 16, 0, 0)

__device__ __forceinline__ short f2bf(float f) {
    union { float f; unsigned u; } a; a.f = f;
    unsigned u = a.u;
    unsigned r = u + 0x7fffu + ((u >> 16) & 1u);   // RNE
    return (short)(r >> 16);
}

// ---------------------------------------------------------------------------
// fp32 -> bf16 conversion for x, Wqkv, Wout
// ---------------------------------------------------------------------------
#define NX4 1048576   // x: 4,194,304 elems / 4
#define NW4  786432   // Wqkv: 3,145,728 / 4
#define NO4  262144   // Wout: 1,048,576 / 4

__global__ __launch_bounds__(256)
void convert_kernel(const float* __restrict__ x, const float* __restrict__ wqkv,
                    const float* __restrict__ wout,
                    short* __restrict__ xb, short* __restrict__ wqkvb,
                    short* __restrict__ woutb)
{
    int i = blockIdx.x * 256 + threadIdx.x;
    const float* src; short* dst; int off;
    if (i < NX4)            { src = x;    dst = xb;    off = i; }
    else if (i < NX4 + NW4) { src = wqkv; dst = wqkvb; off = i - NX4; }
    else if (i < NX4 + NW4 + NO4) { src = wout; dst = woutb; off = i - NX4 - NW4; }
    else return;
    float4 f = ((const float4*)src)[off];
    short4 s;
    s.x = f2bf(f.x); s.y = f2bf(f.y); s.z = f2bf(f.z); s.w = f2bf(f.w);
    ((short4*)dst)[off] = s;
}

// ---------------------------------------------------------------------------
// bf16 MFMA GEMM pieces (byte-identical to round 8).
// ---------------------------------------------------------------------------

__device__ __forceinline__ void gemm_stage(const short* __restrict__ A,
                                           const short* __restrict__ W,
                                           short* As, short* Bs,
                                           int m0, int n0, int k0, int K, int tid)
{
#pragma unroll
    for (int l = 0; l < 4; ++l) {
        int c = l * 256 + tid;
        int row = c >> 3;
        int col8 = (c & 7) ^ (row & 7);
        ASYNC16(&A[(size_t)(m0 + row) * K + k0 + col8 * 8], &As[c * 8]);
        ASYNC16(&W[(size_t)(n0 + row) * K + k0 + col8 * 8], &Bs[c * 8]);
    }
}

__device__ __forceinline__ void gemm_core(const short* As, const short* Bs,
                                          floatx4 acc[4][4], int wm, int wn,
                                          int l15, int quad)
{
#pragma unroll
    for (int kc = 0; kc < 2; ++kc) {
        short8 a[4], b[4];
#pragma unroll
        for (int t = 0; t < 4; ++t) {
            int rowa = wm * 64 + t * 16 + l15;
            int rowb = wn * 64 + t * 16 + l15;
            int sw = (kc * 4 + quad) ^ (l15 & 7);
            a[t] = *(const short8*)&As[(rowa * 8 + sw) * 8];
            b[t] = *(const short8*)&Bs[(rowb * 8 + sw) * 8];
        }
#pragma unroll
        for (int i = 0; i < 4; ++i)
#pragma unroll
            for (int j = 0; j < 4; ++j)
                acc[i][j] = MFMA16(a[i], b[j], acc[i][j]);
    }
}

__global__ __launch_bounds__(256)
void gemm_qkv_bf16(const short* __restrict__ A, const short* __restrict__ W,
                   const float* __restrict__ bias,
                   short* __restrict__ qws, short* __restrict__ kws,
                   short* __restrict__ vtws)
{
    __shared__ short As[128 * 64];
    __shared__ short Bs[128 * 64];
    const int tid = threadIdx.x;
    const int wave = tid >> 6, lane = tid & 63;
    const int l15 = lane & 15, quad = lane >> 4;
    const int wm = wave >> 1, wn = wave & 1;
    const int m0 = blockIdx.y * 128, n0 = blockIdx.x * 128;

    floatx4 acc[4][4];
#pragma unroll
    for (int i = 0; i < 4; ++i)
#pragma unroll
        for (int j = 0; j < 4; ++j) acc[i][j] = (floatx4){0.f, 0.f, 0.f, 0.f};

    for (int k0 = 0; k0 < DMODEL; k0 += 64) {
        __syncthreads();
        gemm_stage(A, W, As, Bs, m0, n0, k0, DMODEL, tid);
        __syncthreads();
        gemm_core(As, Bs, acc, wm, wn, l15, quad);
    }

#pragma unroll
    for (int i = 0; i < 4; ++i) {
#pragma unroll
        for (int j = 0; j < 4; ++j) {
            int n = n0 + wn * 64 + j * 16 + l15;
            int which = n >> 10;
            int rr = n & 1023;
            int h = rr >> 6, d = rr & 63;
            float bv = bias[n];
#pragma unroll
            for (int r = 0; r < 4; ++r) {
                int m = m0 + wm * 64 + i * 16 + quad * 4 + r;
                int bb = m >> 11, t = m & 2047;
                float vv = acc[i][j][r] + bv;
                if (which == 0) vv *= 0.125f;      // fold 1/sqrt(hd) into q
                short val = f2bf(vv);
                size_t hb = (size_t)(bb * NH + h);
                if (which == 0)      qws[(hb * SEQ + t) * HD + d] = val;
                else if (which == 1) kws[(hb * SEQ + t) * HD + d] = val;
                else                 vtws[(hb * HD + d) * SEQ + t] = val;
            }
        }
    }
}

// Out projection: BM=128, BN=64 -> 512 blocks (2/CU).
__global__ __launch_bounds__(256)
void gemm_out_bf16(const short* __restrict__ A, const short* __restrict__ W,
                   const float* __restrict__ bias, float* __restrict__ out)
{
    __shared__ short As[128 * 64];
    __shared__ short Bs[64 * 64];
    const int tid = threadIdx.x;
    const int wave = tid >> 6, lane = tid & 63;
    const int l15 = lane & 15, quad = lane >> 4;
    const int m0 = blockIdx.y * 128, n0 = blockIdx.x * 64;

    floatx4 acc[2][4];
#pragma unroll
    for (int i = 0; i < 2; ++i)
#pragma unroll
        for (int j = 0; j < 4; ++j) acc[i][j] = (floatx4){0.f, 0.f, 0.f, 0.f};

    for (int k0 = 0; k0 < DMODEL; k0 += 64) {
        __syncthreads();
#pragma unroll
        for (int l = 0; l < 4; ++l) {
            int c = l * 256 + tid;
            int row = c >> 3;
            int col8 = (c & 7) ^ (row & 7);
            ASYNC16(&A[(size_t)(m0 + row) * DMODEL + k0 + col8 * 8], &As[c * 8]);
        }
#pragma unroll
        for (int l = 0; l < 2; ++l) {
            int c = l * 256 + tid;
            int row = c >> 3;
            int col8 = (c & 7) ^ (row & 7);
            ASYNC16(&W[(size_t)(n0 + row) * DMODEL + k0 + col8 * 8], &Bs[c * 8]);
        }
        __syncthreads();
#pragma unroll
        for (int kc = 0; kc < 2; ++kc) {
            int sw = (kc * 4 + quad) ^ (l15 & 7);
            short8 a[2], b[4];
#pragma unroll
            for (int i = 0; i < 2; ++i) {
                int rowa = wave * 32 + i * 16 + l15;
                a[i] = *(const short8*)&As[(rowa * 8 + sw) * 8];
            }
#pragma unroll
            for (int j = 0; j < 4; ++j) {
                int rowb = j * 16 + l15;
                b[j] = *(const short8*)&Bs[(rowb * 8 + sw) * 8];
            }
#pragma unroll
            for (int i = 0; i < 2; ++i)
#pragma unroll
                for (int j = 0; j < 4; ++j)
                    acc[i][j] = MFMA16(a[i], b[j], acc[i][j]);
        }
    }

#pragma unroll
    for (int i = 0; i < 2; ++i) {
#pragma unroll
        for (int j = 0; j < 4; ++j) {
            int n = n0 + j * 16 + l15;
            float bv = bias[n];
#pragma unroll
            for (int r = 0; r < 4; ++r) {
                int m = m0 + wave * 32 + i * 16 + quad * 4 + r;
                out[(size_t)m * DMODEL + n] = acc[i][j][r] + bv;
            }
        }
    }
}

// ---------------------------------------------------------------------------
// Transposed-S MFMA flash attention (byte-identical to round 8).
// ---------------------------------------------------------------------------

#define SCAP 24.0f

__global__ __launch_bounds__(256)
void attn_mfma(const short* __restrict__ q, const short* __restrict__ k,
               const short* __restrict__ vt, const int* __restrict__ causal_p,
               short* __restrict__ y)
{
    // heavy-first decode: id = (15-qt)*32 + hb
    const int id = blockIdx.x;
    const int hb = id & 31;
    const int qt = 15 - (id >> 5);
    const int h = hb & 15, b = hb >> 4;

    const int tid = threadIdx.x;
    const int wave = tid >> 6, lane = tid & 63;
    const int l15 = lane & 15, quad = lane >> 4;
    const int q0 = qt * 128;
    const int causal = causal_p[0];
    const float slope = exp2f(-0.5f * (float)(h + 1));

    __shared__ short Ks[2][64 * 64];   // twisted row order, swizzled 16B chunks
    __shared__ short Vs[2][64 * 64];   // [d][t], swizzled

    const size_t base = ((size_t)(b * NH + h)) * SEQ * HD;

    short8 bq[2][2];
    float cc[2];
#pragma unroll
    for (int qt2 = 0; qt2 < 2; ++qt2) {
        int query = q0 + wave * 32 + qt2 * 16 + l15;
        cc[qt2] = SCAP + slope * (float)query;
#pragma unroll
        for (int kc = 0; kc < 2; ++kc)
            bq[qt2][kc] = *(const short8*)&q[base + (size_t)query * HD + kc * 32 + quad * 8];
    }

    float l_acc[2] = {0.f, 0.f};
    floatx4 od[2][4];
#pragma unroll
    for (int qt2 = 0; qt2 < 2; ++qt2)
#pragma unroll
        for (int dt = 0; dt < 4; ++dt) od[qt2][dt] = (floatx4){0.f, 0.f, 0.f, 0.f};

    auto stage = [&](int kt) {
        const int k0s = kt * 64;
        short* Kd = &Ks[kt & 1][0];
        short* Vd = &Vs[kt & 1][0];
#pragma unroll
        for (int l = 0; l < 2; ++l) {
            int c = l * 256 + tid;
            int rho = c >> 3;
            int col8 = (c & 7) ^ (rho & 7);
            int T = rho >> 4, m = rho & 15;
            int kap = (T >> 1) * 32 + (m >> 2) * 8 + (T & 1) * 4 + (m & 3);
            ASYNC16(&k[base + (size_t)(k0s + kap) * HD + col8 * 8], &Kd[c * 8]);
            ASYNC16(&vt[base + (size_t)rho * SEQ + k0s + col8 * 8], &Vd[c * 8]);
        }
    };

    const int ktmax = causal ? (2 * qt + 1) : (SEQ / 64 - 1);
    stage(0);
    for (int kt = 0; kt <= ktmax; ++kt) {
        const int k0 = kt * 64;
        __syncthreads();
        if (kt < ktmax) stage(kt + 1);

        const short* Kc = &Ks[kt & 1][0];
        const short* Vc = &Vs[kt & 1][0];

        short8 ak[4][2], av[4][2];
#pragma unroll
        for (int T = 0; T < 4; ++T) {
            int row = T * 16 + l15;
#pragma unroll
            for (int kc = 0; kc < 2; ++kc) {
                int sw = (kc * 4 + quad) ^ (row & 7);
                ak[T][kc] = *(const short8*)&Kc[(row * 8 + sw) * 8];
                av[T][kc] = *(const short8*)&Vc[(row * 8 + sw) * 8];
            }
        }

        floatx4 st[2][4];
#pragma unroll
        for (int qt2 = 0; qt2 < 2; ++qt2)
#pragma unroll
            for (int T = 0; T < 4; ++T) {
                floatx4 z = (floatx4){0.f, 0.f, 0.f, 0.f};
                z = MFMA16(ak[T][0], bq[qt2][0], z);
                z = MFMA16(ak[T][1], bq[qt2][1], z);
                st[qt2][T] = z;
            }

        const float kq = slope * (float)(k0 + quad * 8);
#pragma unroll
        for (int qt2 = 0; qt2 < 2; ++qt2) {
            const int qmin = q0 + wave * 32 + qt2 * 16;
            const int query = qmin + l15;
            const bool mrt = causal && (k0 + 63 > qmin);
            float lsum = 0.f;
#pragma unroll
            for (int T = 0; T < 4; ++T) {
                const int koff = (T >> 1) * 32 + (T & 1) * 4;
                const float off = kq + slope * (float)koff - cc[qt2];
#pragma unroll
                for (int r = 0; r < 4; ++r) {
                    float t = st[qt2][T][r] + fmaf(slope, (float)r, off);
                    if (mrt && (k0 + quad * 8 + koff + r > query))
                        t = -__builtin_inff();
                    float p = __expf(t);
                    lsum += p;
                    st[qt2][T][r] = p;
                }
            }
            l_acc[qt2] += lsum;
        }

#pragma unroll
        for (int qt2 = 0; qt2 < 2; ++qt2) {
            union { short8 v; short s[8]; } u0, u1;
#pragma unroll
            for (int j = 0; j < 4; ++j) {
                u0.s[j]     = f2bf(st[qt2][0][j]);
                u0.s[4 + j] = f2bf(st[qt2][1][j]);
                u1.s[j]     = f2bf(st[qt2][2][j]);
                u1.s[4 + j] = f2bf(st[qt2][3][j]);
            }
#pragma unroll
            for (int dt = 0; dt < 4; ++dt) {
                floatx4 oo = od[qt2][dt];
                oo = MFMA16(av[dt][0], u0.v, oo);
                oo = MFMA16(av[dt][1], u1.v, oo);
                od[qt2][dt] = oo;
            }
        }
    }

#pragma unroll
    for (int qt2 = 0; qt2 < 2; ++qt2) {
        l_acc[qt2] += __shfl_xor(l_acc[qt2], 16, 64);
        l_acc[qt2] += __shfl_xor(l_acc[qt2], 32, 64);
    }

#pragma unroll
    for (int qt2 = 0; qt2 < 2; ++qt2) {
        const float inv_l = 1.0f / l_acc[qt2];
        const int row = q0 + wave * 32 + qt2 * 16 + l15;
#pragma unroll
        for (int dt = 0; dt < 4; ++dt) {
            short4 sv;
            sv.x = f2bf(od[qt2][dt][0] * inv_l);
            sv.y = f2bf(od[qt2][dt][1] * inv_l);
            sv.z = f2bf(od[qt2][dt][2] * inv_l);
            sv.w = f2bf(od[qt2][dt][3] * inv_l);
            *(short4*)&y[(size_t)(b * SEQ + row) * DMODEL + h * HD + dt * 16 + quad * 4] = sv;
        }
    }
}

// ---------------------------------------------------------------------------
// MEASUREMENT ROUND: the full r8 pipeline is launched TWICE per call.
// The second pass recomputes byte-identical intermediates and d_out (pure
// function of d_in), so every call does the same work and the output is
// unchanged. Kernel-sum S = dur(this) - dur(r8); harness overhead = 450 - S.
// ---------------------------------------------------------------------------

extern "C" void kernel_launch(void* const* d_in, const int* in_sizes, int n_in,
                              void* d_out, int out_size, void* d_ws, size_t ws_size,
                              hipStream_t stream)
{
    const float* x    = (const float*)d_in[0];
    const int*   caus = (const int*)d_in[1];
    // d_in[2] = alibi_bias: recomputed on device
    const float* Wqkv = (const float*)d_in[3];
    const float* bqkv = (const float*)d_in[4];
    const float* Wout = (const float*)d_in[5];
    const float* bout = (const float*)d_in[6];
    float* out = (float*)d_out;

    char* ws = (char*)d_ws;
    short* xb    = (short*)(ws);                       // 8 MB
    short* wqkvb = (short*)(ws + (8u  << 20));         // 6 MB
    short* woutb = (short*)(ws + (14u << 20));         // 2 MB
    short* qws   = (short*)(ws + (16u << 20));         // 8 MB
    short* kws   = (short*)(ws + (24u << 20));         // 8 MB
    short* vtws  = (short*)(ws + (32u << 20));         // 8 MB
    short* yb    = (short*)(ws + (40u << 20));         // 8 MB

    for (int rep = 0; rep < 2; ++rep) {
        convert_kernel<<<8192, 256, 0, stream>>>(x, Wqkv, Wout, xb, wqkvb, woutb);

        dim3 g1(3072 / 128, 4096 / 128);
        gemm_qkv_bf16<<<g1, 256, 0, stream>>>(xb, wqkvb, bqkv, qws, kws, vtws);

        attn_mfma<<<512, 256, 0, stream>>>(qws, kws, vtws, caus, yb);

        dim3 g2(DMODEL / 64, 4096 / 128);
        gemm_out_bf16<<<g2, 256, 0, stream>>>(yb, woutb, bout, out);
    }
}

// Round 10
// 447.828 us; speedup vs baseline: 1.3200x; 1.3200x over previous
//
#include <hip/hip_runtime.h>
#include <cstddef>
#include <cstdint>

#define SEQ    2048
#define DMODEL 1024
#define NH     16
#define HD     64
#define NB     2

typedef __attribute__((ext_vector_type(8))) short short8;
typedef __attribute__((ext_vector_type(4))) float floatx4;

#define MFMA16(a, b, c) __builtin_amdgcn_mfma_f32_16x16x32_bf16((a), (b), (c), 0, 0, 0)

// async 16B global->LDS (wave-uniform base + lane*16 ordering honored by callers)
#define ASYNC16(gsrc, ldst) \
    __builtin_amdgcn_global_load_lds((const __attribute__((address_space(1))) void*)(gsrc), \
                                     (__attribute__((address_space(3))) void*)(ldst), 16, 0, 0)

__device__ __forceinline__ short f2bf(float f) {
    union { float f; unsigned u; } a; a.f = f;
    unsigned u = a.u;
    unsigned r = u + 0x7fffu + ((u >> 16) & 1u);   // RNE
    return (short)(r >> 16);
}

// ---------------------------------------------------------------------------
// fp32 -> bf16 conversion for x, Wqkv, Wout
// ---------------------------------------------------------------------------
#define NX4 1048576   // x: 4,194,304 elems / 4
#define NW4  786432   // Wqkv: 3,145,728 / 4
#define NO4  262144   // Wout: 1,048,576 / 4

__global__ __launch_bounds__(256)
void convert_kernel(const float* __restrict__ x, const float* __restrict__ wqkv,
                    const float* __restrict__ wout,
                    short* __restrict__ xb, short* __restrict__ wqkvb,
                    short* __restrict__ woutb)
{
    int i = blockIdx.x * 256 + threadIdx.x;
    const float* src; short* dst; int off;
    if (i < NX4)            { src = x;    dst = xb;    off = i; }
    else if (i < NX4 + NW4) { src = wqkv; dst = wqkvb; off = i - NX4; }
    else if (i < NX4 + NW4 + NO4) { src = wout; dst = woutb; off = i - NX4 - NW4; }
    else return;
    float4 f = ((const float4*)src)[off];
    short4 s;
    s.x = f2bf(f.x); s.y = f2bf(f.y); s.z = f2bf(f.z); s.w = f2bf(f.w);
    ((short4*)dst)[off] = s;
}

// ---------------------------------------------------------------------------
// QKV GEMM (unchanged from round 8: single-buffer, 128x128, BK=64 — dbuf
// deliberately skipped: 64 KB LDS would drop occupancy 3->2 blocks/CU, the
// m132 regression mode).
// ---------------------------------------------------------------------------

__device__ __forceinline__ void gemm_stage(const short* __restrict__ A,
                                           const short* __restrict__ W,
                                           short* As, short* Bs,
                                           int m0, int n0, int k0, int K, int tid)
{
#pragma unroll
    for (int l = 0; l < 4; ++l) {
        int c = l * 256 + tid;
        int row = c >> 3;
        int col8 = (c & 7) ^ (row & 7);
        ASYNC16(&A[(size_t)(m0 + row) * K + k0 + col8 * 8], &As[c * 8]);
        ASYNC16(&W[(size_t)(n0 + row) * K + k0 + col8 * 8], &Bs[c * 8]);
    }
}

__device__ __forceinline__ void gemm_core(const short* As, const short* Bs,
                                          floatx4 acc[4][4], int wm, int wn,
                                          int l15, int quad)
{
#pragma unroll
    for (int kc = 0; kc < 2; ++kc) {
        short8 a[4], b[4];
#pragma unroll
        for (int t = 0; t < 4; ++t) {
            int rowa = wm * 64 + t * 16 + l15;
            int rowb = wn * 64 + t * 16 + l15;
            int sw = (kc * 4 + quad) ^ (l15 & 7);
            a[t] = *(const short8*)&As[(rowa * 8 + sw) * 8];
            b[t] = *(const short8*)&Bs[(rowb * 8 + sw) * 8];
        }
#pragma unroll
        for (int i = 0; i < 4; ++i)
#pragma unroll
            for (int j = 0; j < 4; ++j)
                acc[i][j] = MFMA16(a[i], b[j], acc[i][j]);
    }
}

__global__ __launch_bounds__(256)
void gemm_qkv_bf16(const short* __restrict__ A, const short* __restrict__ W,
                   const float* __restrict__ bias,
                   short* __restrict__ qws, short* __restrict__ kws,
                   short* __restrict__ vtws)
{
    __shared__ short As[128 * 64];
    __shared__ short Bs[128 * 64];
    const int tid = threadIdx.x;
    const int wave = tid >> 6, lane = tid & 63;
    const int l15 = lane & 15, quad = lane >> 4;
    const int wm = wave >> 1, wn = wave & 1;
    const int m0 = blockIdx.y * 128, n0 = blockIdx.x * 128;

    floatx4 acc[4][4];
#pragma unroll
    for (int i = 0; i < 4; ++i)
#pragma unroll
        for (int j = 0; j < 4; ++j) acc[i][j] = (floatx4){0.f, 0.f, 0.f, 0.f};

    for (int k0 = 0; k0 < DMODEL; k0 += 64) {
        __syncthreads();
        gemm_stage(A, W, As, Bs, m0, n0, k0, DMODEL, tid);
        __syncthreads();
        gemm_core(As, Bs, acc, wm, wn, l15, quad);
    }

#pragma unroll
    for (int i = 0; i < 4; ++i) {
#pragma unroll
        for (int j = 0; j < 4; ++j) {
            int n = n0 + wn * 64 + j * 16 + l15;
            int which = n >> 10;
            int rr = n & 1023;
            int h = rr >> 6, d = rr & 63;
            float bv = bias[n];
#pragma unroll
            for (int r = 0; r < 4; ++r) {
                int m = m0 + wm * 64 + i * 16 + quad * 4 + r;
                int bb = m >> 11, t = m & 2047;
                float vv = acc[i][j][r] + bv;
                if (which == 0) vv *= 0.125f;      // fold 1/sqrt(hd) into q
                short val = f2bf(vv);
                size_t hb = (size_t)(bb * NH + h);
                if (which == 0)      qws[(hb * SEQ + t) * HD + d] = val;
                else if (which == 1) kws[(hb * SEQ + t) * HD + d] = val;
                else                 vtws[(hb * HD + d) * SEQ + t] = val;
            }
        }
    }
}

// ---------------------------------------------------------------------------
// Out projection: BM=128, BN=64, 512 blocks. ROUND 10: single-barrier LDS
// double-buffer (r8-proven pattern): stage(k+1) issued right after the barrier
// that publishes buf[k&1]; loads complete during compute. 48 KB LDS -> 3
// blocks/CU by LDS >= the 2 resident by grid.
// ---------------------------------------------------------------------------

__global__ __launch_bounds__(256)
void gemm_out_bf16(const short* __restrict__ A, const short* __restrict__ W,
                   const float* __restrict__ bias, float* __restrict__ out)
{
    __shared__ short As[2][128 * 64];
    __shared__ short Bs[2][64 * 64];
    const int tid = threadIdx.x;
    const int wave = tid >> 6, lane = tid & 63;
    const int l15 = lane & 15, quad = lane >> 4;
    const int m0 = blockIdx.y * 128, n0 = blockIdx.x * 64;

    floatx4 acc[2][4];
#pragma unroll
    for (int i = 0; i < 2; ++i)
#pragma unroll
        for (int j = 0; j < 4; ++j) acc[i][j] = (floatx4){0.f, 0.f, 0.f, 0.f};

    auto stage = [&](int ki) {
        const int k0 = ki * 64;
        short* Ad = &As[ki & 1][0];
        short* Bd = &Bs[ki & 1][0];
#pragma unroll
        for (int l = 0; l < 4; ++l) {
            int c = l * 256 + tid;
            int row = c >> 3;
            int col8 = (c & 7) ^ (row & 7);
            ASYNC16(&A[(size_t)(m0 + row) * DMODEL + k0 + col8 * 8], &Ad[c * 8]);
        }
#pragma unroll
        for (int l = 0; l < 2; ++l) {
            int c = l * 256 + tid;
            int row = c >> 3;
            int col8 = (c & 7) ^ (row & 7);
            ASYNC16(&W[(size_t)(n0 + row) * DMODEL + k0 + col8 * 8], &Bd[c * 8]);
        }
    };

    stage(0);
    for (int ki = 0; ki < DMODEL / 64; ++ki) {
        __syncthreads();               // buf[ki&1] published; prev reads of other buf done
        if (ki < DMODEL / 64 - 1) stage(ki + 1);
        const short* Ac = &As[ki & 1][0];
        const short* Bc = &Bs[ki & 1][0];
#pragma unroll
        for (int kc = 0; kc < 2; ++kc) {
            int sw = (kc * 4 + quad) ^ (l15 & 7);
            short8 a[2], b[4];
#pragma unroll
            for (int i = 0; i < 2; ++i) {
                int rowa = wave * 32 + i * 16 + l15;
                a[i] = *(const short8*)&Ac[(rowa * 8 + sw) * 8];
            }
#pragma unroll
            for (int j = 0; j < 4; ++j) {
                int rowb = j * 16 + l15;
                b[j] = *(const short8*)&Bc[(rowb * 8 + sw) * 8];
            }
#pragma unroll
            for (int i = 0; i < 2; ++i)
#pragma unroll
                for (int j = 0; j < 4; ++j)
                    acc[i][j] = MFMA16(a[i], b[j], acc[i][j]);
        }
    }

#pragma unroll
    for (int i = 0; i < 2; ++i) {
#pragma unroll
        for (int j = 0; j < 4; ++j) {
            int n = n0 + j * 16 + l15;
            float bv = bias[n];
#pragma unroll
            for (int r = 0; r < 4; ++r) {
                int m = m0 + wave * 32 + i * 16 + quad * 4 + r;
                out[(size_t)m * DMODEL + n] = acc[i][j][r] + bv;
            }
        }
    }
}

// ---------------------------------------------------------------------------
// Transposed-S MFMA flash attention, fixed-cap softmax, heavy-first, dbuf.
// ROUND 10: 8-wave (512-thread) blocks, 16 queries/wave, same 128-query tile.
// Attn is latency-bound (throughput floor ~7 us vs ~50 us observed): doubling
// waves/CU (8 -> 16) doubles cross-wave overlap at every chain stall. Per-wave
// state halves (~100 VGPR -> 4 waves/SIMD fits).
// ---------------------------------------------------------------------------

#define SCAP 24.0f

__global__ __launch_bounds__(512)
void attn_mfma(const short* __restrict__ q, const short* __restrict__ k,
               const short* __restrict__ vt, const int* __restrict__ causal_p,
               short* __restrict__ y)
{
    // heavy-first decode: id = (15-qt)*32 + hb
    const int id = blockIdx.x;
    const int hb = id & 31;
    const int qt = 15 - (id >> 5);
    const int h = hb & 15, b = hb >> 4;

    const int tid = threadIdx.x;
    const int wave = tid >> 6, lane = tid & 63;   // wave 0..7
    const int l15 = lane & 15, quad = lane >> 4;
    const int q0 = qt * 128;
    const int causal = causal_p[0];
    const float slope = exp2f(-0.5f * (float)(h + 1));

    __shared__ short Ks[2][64 * 64];   // twisted row order, swizzled 16B chunks
    __shared__ short Vs[2][64 * 64];   // [d][t], swizzled

    const size_t base = ((size_t)(b * NH + h)) * SEQ * HD;

    // Q B-frags: this wave owns queries q0 + wave*16 + l15
    const int query = q0 + wave * 16 + l15;
    const float cc = SCAP + slope * (float)query;
    short8 bq[2];
#pragma unroll
    for (int kc = 0; kc < 2; ++kc)
        bq[kc] = *(const short8*)&q[base + (size_t)query * HD + kc * 32 + quad * 8];

    float l_acc = 0.f;
    floatx4 od[4];
#pragma unroll
    for (int dt = 0; dt < 4; ++dt) od[dt] = (floatx4){0.f, 0.f, 0.f, 0.f};

    auto stage = [&](int kt) {
        const int k0s = kt * 64;
        short* Kd = &Ks[kt & 1][0];
        short* Vd = &Vs[kt & 1][0];
        // 512 chunks per tensor, 512 threads: 1 chunk each (LDS dest lane*16-linear)
        int c = tid;
        int rho = c >> 3;
        int col8 = (c & 7) ^ (rho & 7);
        int T = rho >> 4, m = rho & 15;
        int kap = (T >> 1) * 32 + (m >> 2) * 8 + (T & 1) * 4 + (m & 3);
        ASYNC16(&k[base + (size_t)(k0s + kap) * HD + col8 * 8], &Kd[c * 8]);
        ASYNC16(&vt[base + (size_t)rho * SEQ + k0s + col8 * 8], &Vd[c * 8]);
    };

    const int ktmax = causal ? (2 * qt + 1) : (SEQ / 64 - 1);
    stage(0);
    for (int kt = 0; kt <= ktmax; ++kt) {
        const int k0 = kt * 64;
        __syncthreads();               // buf[kt&1] published; prev reads of other buf done
        if (kt < ktmax) stage(kt + 1);

        const short* Kc = &Ks[kt & 1][0];
        const short* Vc = &Vs[kt & 1][0];

        // K and V A-frags
        short8 ak[4][2], av[4][2];
#pragma unroll
        for (int T = 0; T < 4; ++T) {
            int row = T * 16 + l15;
#pragma unroll
            for (int kc = 0; kc < 2; ++kc) {
                int sw = (kc * 4 + quad) ^ (row & 7);
                ak[T][kc] = *(const short8*)&Kc[(row * 8 + sw) * 8];
                av[T][kc] = *(const short8*)&Vc[(row * 8 + sw) * 8];
            }
        }

        // S^T = K Q^T
        floatx4 st[4];
#pragma unroll
        for (int T = 0; T < 4; ++T) {
            floatx4 z = (floatx4){0.f, 0.f, 0.f, 0.f};
            z = MFMA16(ak[T][0], bq[0], z);
            z = MFMA16(ak[T][1], bq[1], z);
            st[T] = z;
        }

        // softmax (fixed cap): p = exp(s + slope*key - SCAP - slope*query)
        const float kq = slope * (float)(k0 + quad * 8);
        const int qmin = q0 + wave * 16;
        const bool mrt = causal && (k0 + 63 > qmin);
        float lsum = 0.f;
#pragma unroll
        for (int T = 0; T < 4; ++T) {
            const int koff = (T >> 1) * 32 + (T & 1) * 4;
            const float off = kq + slope * (float)koff - cc;
#pragma unroll
            for (int r = 0; r < 4; ++r) {
                float t = st[T][r] + fmaf(slope, (float)r, off);
                if (mrt && (k0 + quad * 8 + koff + r > query))
                    t = -__builtin_inff();
                float p = __expf(t);
                lsum += p;
                st[T][r] = p;
            }
        }
        l_acc += lsum;

        // P b-frags straight from own registers; O^T += V^T P
        union { short8 v; short s[8]; } u0, u1;
#pragma unroll
        for (int j = 0; j < 4; ++j) {
            u0.s[j]     = f2bf(st[0][j]);
            u0.s[4 + j] = f2bf(st[1][j]);
            u1.s[j]     = f2bf(st[2][j]);
            u1.s[4 + j] = f2bf(st[3][j]);
        }
#pragma unroll
        for (int dt = 0; dt < 4; ++dt) {
            floatx4 oo = od[dt];
            oo = MFMA16(av[dt][0], u0.v, oo);
            oo = MFMA16(av[dt][1], u1.v, oo);
            od[dt] = oo;
        }
    }

    // reduce l over the 4 quads (queries live in l15; key-partials in quad)
    l_acc += __shfl_xor(l_acc, 16, 64);
    l_acc += __shfl_xor(l_acc, 32, 64);

    // epilogue: y (B,T,D) bf16; lane holds O^T[d = dt*16+quad*4+r][query=l15]
    const float inv_l = 1.0f / l_acc;
#pragma unroll
    for (int dt = 0; dt < 4; ++dt) {
        short4 sv;
        sv.x = f2bf(od[dt][0] * inv_l);
        sv.y = f2bf(od[dt][1] * inv_l);
        sv.z = f2bf(od[dt][2] * inv_l);
        sv.w = f2bf(od[dt][3] * inv_l);
        *(short4*)&y[(size_t)(b * SEQ + query) * DMODEL + h * HD + dt * 16 + quad * 4] = sv;
    }
}

// ---------------------------------------------------------------------------

extern "C" void kernel_launch(void* const* d_in, const int* in_sizes, int n_in,
                              void* d_out, int out_size, void* d_ws, size_t ws_size,
                              hipStream_t stream)
{
    const float* x    = (const float*)d_in[0];
    const int*   caus = (const int*)d_in[1];
    // d_in[2] = alibi_bias: recomputed on device
    const float* Wqkv = (const float*)d_in[3];
    const float* bqkv = (const float*)d_in[4];
    const float* Wout = (const float*)d_in[5];
    const float* bout = (const float*)d_in[6];
    float* out = (float*)d_out;

    char* ws = (char*)d_ws;
    short* xb    = (short*)(ws);                       // 8 MB
    short* wqkvb = (short*)(ws + (8u  << 20));         // 6 MB
    short* woutb = (short*)(ws + (14u << 20));         // 2 MB
    short* qws   = (short*)(ws + (16u << 20));         // 8 MB
    short* kws   = (short*)(ws + (24u << 20));         // 8 MB
    short* vtws  = (short*)(ws + (32u << 20));         // 8 MB
    short* yb    = (short*)(ws + (40u << 20));         // 8 MB

    convert_kernel<<<8192, 256, 0, stream>>>(x, Wqkv, Wout, xb, wqkvb, woutb);

    dim3 g1(3072 / 128, 4096 / 128);
    gemm_qkv_bf16<<<g1, 256, 0, stream>>>(xb, wqkvb, bqkv, qws, kws, vtws);

    attn_mfma<<<512, 512, 0, stream>>>(qws, kws, vtws, caus, yb);

    dim3 g2(DMODEL / 64, 4096 / 128);
    gemm_out_bf16<<<g2, 256, 0, stream>>>(yb, woutb, bout, out);
}